// Round 7
// baseline (257.744 us; speedup 1.0000x reference)
//
#include <hip/hip_runtime.h>
#include <hip/hip_bf16.h>

#define N_TOKENS 16384
#define DIM      2048
#define NEXP     64
#define TOPK     8
#define LOSCALE  2048.0f      // 2^11, exact power of two
#define NBLOCKS  512          // 32 tokens per block
#define LSTRIDE  66           // exchange stride: <=2-way bank aliasing
#define NREP     32           // replicated aux accumulators

typedef _Float16 half8   __attribute__((ext_vector_type(8)));
typedef float    floatx4 __attribute__((ext_vector_type(4)));

// ---------------------------------------------------------------------------
// Kernel 0: split W (64x2048 fp32) into f16 hi/lo planes.
//   whi = (f16)w;  wlo = (f16)((w - (f32)whi) * 2^11)
// ---------------------------------------------------------------------------
__global__ __launch_bounds__(256) void wprep_kernel(const float* __restrict__ W,
                                                    _Float16* __restrict__ Whi,
                                                    _Float16* __restrict__ Wlo) {
    int i = blockIdx.x * 256 + threadIdx.x;           // grid 512 -> 131072
    float w = W[i];
    _Float16 h = (_Float16)w;
    Whi[i] = h;
    Wlo[i] = (_Float16)((w - (float)h) * LOSCALE);
}

// ---------------------------------------------------------------------------
// Free-running MoE router kernel. 512 blocks x 4 waves; block = 32 tokens;
// waves K-split (512 k each). R0 topology (direct fragment loads, no LDS,
// no barriers in the K-loop) with the one flaw removed:
//
// R0-R6 evidence: every structure so far drained vmcnt to 0 once per
// chunk/round (R0: arn->ar rotation copies; R5: __syncthreads; R6: DMA
// swizzle de-coalesced the sources) and all 512 blocks convoyed in
// lockstep -> memory served a burst then idled; aggregate A-service
// pinned at ~0.7-1.3 TB/s with all pipes <15% busy. Fix here:
//   - TWO named register sets (S0/S1), consumed and reloaded IN PLACE
//     (unroll-by-2, static guards, no copies): consuming S0 waits only
//     past S1's 12 in-flight loads -> compiler emits counted vmcnt(~12),
//     never 0; ~24 loads/wave continuously in flight.
//   - no barriers until the epilogue -> waves/blocks free-run and
//     desynchronize; memory system stays uniformly busy.
//   - no __launch_bounds__ arg2 (R1: spills; R2: pipeline destroyed).
//     VGPR ~180 expected; spills would show as WRITE_SIZE >> 1.3 MB.
//   - K-loop: f16-split MFMA (a ~ ah + al/2^11; dropped ll term
//     ~2^-22|a||b|, validated index-exact previously).
//   - epilogue: R0's validated exchange + softmax + rank-select
//     (lax.top_k semantics) + NREP-replicated aux reduction.
// ---------------------------------------------------------------------------
__global__ __launch_bounds__(256) void moe_kernel(const float* __restrict__ A,
                                                  const _Float16* __restrict__ Whi,
                                                  const _Float16* __restrict__ Wlo,
                                                  float* __restrict__ out_w,
                                                  float* __restrict__ out_i,
                                                  float* __restrict__ out_aux,
                                                  float* __restrict__ cnt_ws,
                                                  float* __restrict__ sp_ws,
                                                  unsigned int* __restrict__ ticket) {
    __shared__ float lds[4 * 32 * LSTRIDE];
    __shared__ float s_cnt[NEXP];
    __shared__ float s_sp[NEXP];
    __shared__ int   s_last;

    const int lane  = threadIdx.x & 63;
    const int wv    = threadIdx.x >> 6;      // k-slab 0..3
    const int row16 = lane & 15;
    const int quad  = lane >> 4;
    const int tbase = blockIdx.x * 32;
    const int kbase = wv * 512;

    if (threadIdx.x < NEXP) { s_cnt[threadIdx.x] = 0.f; s_sp[threadIdx.x] = 0.f; }

    floatx4 acc0[2][4] = {};   // hi*hi
    floatx4 acc1[2][4] = {};   // hi*lo_s + lo_s*hi (carries 2^11)

    const float* ap0 = A + (size_t)(tbase + row16) * DIM + quad * 8 + kbase;
    const float* ap1 = ap0 + (size_t)16 * DIM;
    const size_t boff = (size_t)row16 * DIM + quad * 8 + kbase;

    // two named in-place register sets (no rotation copies!)
    float4 ar0[2][2], ar1[2][2];
    half8  bh0[4], bl0[4], bh1[4], bl1[4];

    // load one chunk set; KC = byte-free float offset of chunk within slab
#define LOADSET(AR, BH, BL, KC)                                               \
    do {                                                                      \
        AR[0][0] = *(const float4*)(ap0 + (KC));                              \
        AR[0][1] = *(const float4*)(ap0 + (KC) + 4);                          \
        AR[1][0] = *(const float4*)(ap1 + (KC));                              \
        AR[1][1] = *(const float4*)(ap1 + (KC) + 4);                          \
        _Pragma("unroll")                                                     \
        for (int _nt = 0; _nt < 4; ++_nt) {                                   \
            BH[_nt] = *(const half8*)(Whi + (size_t)_nt * 16 * DIM + boff + (KC)); \
            BL[_nt] = *(const half8*)(Wlo + (size_t)_nt * 16 * DIM + boff + (KC)); \
        }                                                                     \
    } while (0)

    // split + 24 MFMAs consuming one set
#define CONSUME(AR, BH, BL)                                                   \
    do {                                                                      \
        half8 _ah[2], _al[2];                                                 \
        _Pragma("unroll")                                                     \
        for (int _mt = 0; _mt < 2; ++_mt) {                                   \
            float _av[8] = {AR[_mt][0].x, AR[_mt][0].y, AR[_mt][0].z, AR[_mt][0].w, \
                            AR[_mt][1].x, AR[_mt][1].y, AR[_mt][1].z, AR[_mt][1].w};\
            _Pragma("unroll")                                                 \
            for (int _j = 0; _j < 8; ++_j) {                                  \
                _Float16 _h = (_Float16)_av[_j];                              \
                _ah[_mt][_j] = _h;                                            \
                _al[_mt][_j] = (_Float16)((_av[_j] - (float)_h) * LOSCALE);   \
            }                                                                 \
        }                                                                     \
        _Pragma("unroll")                                                     \
        for (int _mt = 0; _mt < 2; ++_mt)                                     \
            _Pragma("unroll")                                                 \
            for (int _nt = 0; _nt < 4; ++_nt) {                               \
                acc0[_mt][_nt] = __builtin_amdgcn_mfma_f32_16x16x32_f16(_ah[_mt], BH[_nt], acc0[_mt][_nt], 0, 0, 0); \
                acc1[_mt][_nt] = __builtin_amdgcn_mfma_f32_16x16x32_f16(_ah[_mt], BL[_nt], acc1[_mt][_nt], 0, 0, 0); \
                acc1[_mt][_nt] = __builtin_amdgcn_mfma_f32_16x16x32_f16(_al[_mt], BH[_nt], acc1[_mt][_nt], 0, 0, 0); \
            }                                                                 \
    } while (0)

    // prologue: chunks 0 and 1 in flight
    LOADSET(ar0, bh0, bl0, 0);
    LOADSET(ar1, bh1, bl1, 32);

    // main loop: 8 unrolled double-chunks; consume in place, reload in place
    #pragma unroll
    for (int u = 0; u < 8; ++u) {
        CONSUME(ar0, bh0, bl0);                       // chunk 2u
        if (u < 7) LOADSET(ar0, bh0, bl0, (2 * u + 2) * 32);
        CONSUME(ar1, bh1, bl1);                       // chunk 2u+1
        if (u < 7) LOADSET(ar1, bh1, bl1, (2 * u + 3) * 32);
    }

    // partial logits -> LDS ; C layout: col=lane&15 (expert), row=quad*4+reg
    const float inv = 1.0f / LOSCALE;
    #pragma unroll
    for (int mt = 0; mt < 2; ++mt)
        #pragma unroll
        for (int nt = 0; nt < 4; ++nt)
            #pragma unroll
            for (int reg = 0; reg < 4; ++reg) {
                int tok = mt * 16 + quad * 4 + reg;
                lds[(wv * 32 + tok) * LSTRIDE + nt * 16 + row16] =
                    acc0[mt][nt][reg] + acc1[mt][nt][reg] * inv;
            }
    __syncthreads();

    // epilogue: wave wv handles tokens [wv*8, wv*8+8); lane = expert
    float sp = 0.f, cnt = 0.f;
    for (int i = 0; i < 8; ++i) {
        int t = wv * 8 + i;
        float lg = (lds[t * LSTRIDE + lane]              + lds[(32 + t) * LSTRIDE + lane])
                 + (lds[(64 + t) * LSTRIDE + lane]       + lds[(96 + t) * LSTRIDE + lane]);

        float m = lg;
        #pragma unroll
        for (int off = 32; off; off >>= 1) m = fmaxf(m, __shfl_xor(m, off));
        float e = expf(lg - m);
        float ssum = e;
        #pragma unroll
        for (int off = 32; off; off >>= 1) ssum += __shfl_xor(ssum, off);
        float score = e / ssum;
        sp += score;

        int rank = 0;
        #pragma unroll
        for (int j = 0; j < 64; ++j) {
            float sj = __shfl(score, j);
            rank += (sj > score) || (sj == score && j < lane);
        }
        bool sel = rank < TOPK;

        float v = sel ? score : 0.f;
        #pragma unroll
        for (int off = 32; off; off >>= 1) v += __shfl_xor(v, off);

        if (sel) {
            out_w[(size_t)(tbase + t) * TOPK + rank] = score / v;
            out_i[(size_t)(tbase + t) * TOPK + rank] = (float)lane;
            cnt += 1.f;
        }
    }

    atomicAdd(&s_sp[lane], sp);
    atomicAdd(&s_cnt[lane], cnt);
    __syncthreads();
    const int rep = (blockIdx.x & (NREP - 1)) * NEXP;
    if (threadIdx.x < 64)       atomicAdd(&cnt_ws[rep + threadIdx.x], s_cnt[threadIdx.x]);
    else if (threadIdx.x < 128) atomicAdd(&sp_ws[rep + threadIdx.x - 64], s_sp[threadIdx.x - 64]);

    // release our atomics, then take a ticket; last block finalizes
    __threadfence();
    __syncthreads();
    if (threadIdx.x == 0)
        s_last = (atomicAdd(ticket, 1u) == (unsigned)(gridDim.x - 1));
    __syncthreads();
    if (s_last && threadIdx.x < 64) {
        float c = 0.f, p = 0.f;
        #pragma unroll
        for (int r = 0; r < NREP; ++r) {
            c += atomicAdd(&cnt_ws[r * NEXP + threadIdx.x], 0.f);   // device-scope read
            p += atomicAdd(&sp_ws [r * NEXP + threadIdx.x], 0.f);
        }
        float v = (c / (float)(N_TOKENS * TOPK)) * (p / (float)N_TOKENS);
        #pragma unroll
        for (int off = 32; off; off >>= 1) v += __shfl_xor(v, off);
        if (threadIdx.x == 0) out_aux[0] = 0.001f * (float)NEXP * v;
    }
}

extern "C" void kernel_launch(void* const* d_in, const int* in_sizes, int n_in,
                              void* d_out, int out_size, void* d_ws, size_t ws_size,
                              hipStream_t stream) {
    const float* A = (const float*)d_in[0];   // hidden_states (16384 x 2048)
    const float* W = (const float*)d_in[1];   // weight        (64 x 2048)
    float* out = (float*)d_out;

    _Float16*     whi    = (_Float16*)d_ws;
    _Float16*     wlo    = whi + (size_t)NEXP * DIM;
    float*        cnt_ws = (float*)(wlo + (size_t)NEXP * DIM);
    float*        sp_ws  = cnt_ws + (size_t)NREP * NEXP;
    unsigned int* ticket = (unsigned int*)(sp_ws + (size_t)NREP * NEXP);

    // zero cnt(8KB) + sp(8KB) + ticket(4B)
    hipMemsetAsync(cnt_ws, 0, 2 * NREP * NEXP * sizeof(float) + sizeof(unsigned int), stream);

    hipLaunchKernelGGL(wprep_kernel, dim3(NEXP * DIM / 256), dim3(256), 0, stream,
                       W, whi, wlo);

    float* out_w = out;
    float* out_i = out + (size_t)N_TOKENS * TOPK;
    float* out_a = out + 2 * (size_t)N_TOKENS * TOPK;

    hipLaunchKernelGGL(moe_kernel, dim3(NBLOCKS), dim3(256), 0, stream,
                       A, whi, wlo, out_w, out_i, out_a, cnt_ws, sp_ws, ticket);
}

// Round 8
// 253.039 us; speedup vs baseline: 1.0186x; 1.0186x over previous
//
#include <hip/hip_runtime.h>
#include <hip/hip_bf16.h>

#define N_TOKENS 16384
#define DIM      2048
#define NEXP     64
#define TOPK     8
#define LOSCALE  2048.0f      // 2^11, exact power of two
#define NBLOCKS  512          // 32 tokens per block
#define TOKPB    32
#define LSTRIDE  66           // exchange stride: <=2-way bank aliasing
#define NREP     32           // replicated aux accumulators
#define KROUND   256          // floats per staging round (1024 B per token row)
#define NR       8            // rounds (K = 2048)
#define SPAD     260          // padded stage row (1040 B == 16 mod 128 -> bank spread)

typedef _Float16 half8   __attribute__((ext_vector_type(8)));
typedef float    floatx4 __attribute__((ext_vector_type(4)));

// ---------------------------------------------------------------------------
// Kernel 0: split W (64x2048 fp32) into f16 hi/lo planes.
//   whi = (f16)w;  wlo = (f16)((w - (f32)whi) * 2^11)
// ---------------------------------------------------------------------------
__global__ __launch_bounds__(256) void wprep_kernel(const float* __restrict__ W,
                                                    _Float16* __restrict__ Whi,
                                                    _Float16* __restrict__ Wlo) {
    int i = blockIdx.x * 256 + threadIdx.x;
    float w = W[i];
    _Float16 h = (_Float16)w;
    Whi[i] = h;
    Wlo[i] = (_Float16)((w - (float)h) * LOSCALE);
}

// async 16B global->LDS DMA: per-lane source, linear LDS dest (base + lane*16)
__device__ __forceinline__ void gl_lds16(const float* src, float* lds_dst) {
    __builtin_amdgcn_global_load_lds(
        (const __attribute__((address_space(1))) unsigned int*)src,
        (__attribute__((address_space(3))) unsigned int*)lds_dst,
        16, 0, 0);
}

// split 8 f32 -> f16 hi/lo half8 pair (hi = rn(f32), lo = (f32-hi)*2^11)
__device__ __forceinline__ void split8(const floatx4& f0, const floatx4& f1,
                                       half8& H, half8& L) {
    #pragma unroll
    for (int j = 0; j < 4; ++j) {
        _Float16 h = (_Float16)f0[j];
        H[j] = h; L[j] = (_Float16)((f0[j] - (float)h) * LOSCALE);
    }
    #pragma unroll
    for (int j = 0; j < 4; ++j) {
        _Float16 h = (_Float16)f1[j];
        H[4 + j] = h; L[4 + j] = (_Float16)((f1[j] - (float)h) * LOSCALE);
    }
}

// ---------------------------------------------------------------------------
// Dense-line DMA MoE router. 512 blocks x 4 waves; block = 32 tokens; waves
// split EXPERTS (16 each, full K, acc = 16 VGPR).
//
// R0/R5/R6/R7 invariant: A-service pinned at 0.7-1.3 TB/s with all pipes
// <15% busy, while a float4 copy kernel does 6.3 TB/s. The difference is
// per-instruction line density: the fragment-direct loads scattered 64
// lanes over 16 rows 8KB apart (16 sparse lines/instr); a copy kernel
// reads 1024B contiguous. R7 (VGPR 116 = R0 exactly) proved the compiler
// already pipelines registers; the schedule was never the limit -- the
// request pattern was. This kernel makes every A instruction DENSE:
//   - K-round = 256 floats: ONE global_load_lds per token row per round
//     (64 lanes x 16B consecutive = 1024B contiguous).
//   - stage[2][32][260] f32 (pad->rows spread banks; pad between rows so
//     each 1KB DMA dest stays linear). Split f32->f16 on read (VALU idle).
//   - counted vmcnt only: end of round r: issue B(r+1) (16, L2-hit),
//     vmcnt(16) drains own DMA(r+1) & leaves B(r+1) in flight, raw
//     s_barrier (+sched_barrier fences), then DMA(r+2) into buf[r&1].
//     Never vmcnt(0) in the loop; DMA has a full round to land.
//   - race audit: buf written only after the barrier following its last
//     read; read only after own-DMA drain + barrier. DMA mechanics
//     validated in R6 (passed).
//   - epilogue: R5's validated single-plane exchange + softmax +
//     rank-select (lax.top_k semantics) + NREP aux reduction.
// ---------------------------------------------------------------------------
__global__ __launch_bounds__(256) void moe_kernel(const float* __restrict__ A,
                                                  const _Float16* __restrict__ Whi,
                                                  const _Float16* __restrict__ Wlo,
                                                  float* __restrict__ out_w,
                                                  float* __restrict__ out_i,
                                                  float* __restrict__ out_aux,
                                                  float* __restrict__ cnt_ws,
                                                  float* __restrict__ sp_ws,
                                                  unsigned int* __restrict__ ticket) {
    __shared__ float stage[2][TOKPB][SPAD];     // 66.6 KB
    __shared__ float xch[TOKPB * LSTRIDE];      // 8.4 KB
    __shared__ float s_cnt[NEXP];
    __shared__ float s_sp[NEXP];
    __shared__ int   s_last;

    const int tid   = threadIdx.x;
    const int lane  = tid & 63;
    const int wv    = tid >> 6;          // expert tile 0..3
    const int row16 = lane & 15;
    const int quad  = lane >> 4;
    const int tbase = blockIdx.x * TOKPB;

    if (tid < NEXP) { s_cnt[tid] = 0.f; s_sp[tid] = 0.f; }

    // DMA sources: wave wv stages tokens [wv*8, wv*8+8); lane covers 16B
    const float* asrc[8];
    #pragma unroll
    for (int i = 0; i < 8; ++i)
        asrc[i] = A + (size_t)(tbase + wv * 8 + i) * DIM + lane * 4;

    // MFMA role: wave wv's 16 expert rows
    const _Float16* bhp = Whi + (size_t)(wv * 16 + row16) * DIM + quad * 8;
    const _Float16* blp = Wlo + (size_t)(wv * 16 + row16) * DIM + quad * 8;

    floatx4 acc0[2] = {};   // hi*hi         (mt = 0,1)
    floatx4 acc1[2] = {};   // hi*lo + lo*hi (carries 2^11)
    half8 bh[8], bl[8];     // current round's B chunks (64 VGPR)

    // ---- prologue: DMA(0), B(0), DMA(1); drain DMA(0)+B(0), keep DMA(1) ----
    #pragma unroll
    for (int i = 0; i < 8; ++i) gl_lds16(asrc[i], &stage[0][wv * 8 + i][0]);
    #pragma unroll
    for (int c = 0; c < 8; ++c) {
        bh[c] = *(const half8*)(bhp + c * 32);
        bl[c] = *(const half8*)(blp + c * 32);
    }
    #pragma unroll
    for (int i = 0; i < 8; ++i) gl_lds16(asrc[i] + KROUND, &stage[1][wv * 8 + i][0]);

    __builtin_amdgcn_sched_barrier(0);
    asm volatile("s_waitcnt vmcnt(8)" ::: "memory");   // DMA(0)+B(0) done; DMA(1) flies
    __builtin_amdgcn_sched_barrier(0);
    __builtin_amdgcn_s_barrier();
    __builtin_amdgcn_sched_barrier(0);

    // ---- main loop: 8 rounds of K=256 ----
    for (int r = 0; r < NR; ++r) {
        const float* sb = &stage[r & 1][0][0];

        #pragma unroll
        for (int c = 0; c < 8; ++c) {
            #pragma unroll
            for (int mt = 0; mt < 2; ++mt) {
                const float* p = sb + (mt * 16 + row16) * SPAD + c * 32 + quad * 8;
                floatx4 f0 = *(const floatx4*)p;
                floatx4 f1 = *(const floatx4*)(p + 4);
                half8 ah, al; split8(f0, f1, ah, al);
                acc0[mt] = __builtin_amdgcn_mfma_f32_16x16x32_f16(ah, bh[c], acc0[mt], 0, 0, 0);
                acc1[mt] = __builtin_amdgcn_mfma_f32_16x16x32_f16(ah, bl[c], acc1[mt], 0, 0, 0);
                acc1[mt] = __builtin_amdgcn_mfma_f32_16x16x32_f16(al, bh[c], acc1[mt], 0, 0, 0);
            }
        }

        if (r < NR - 1) {
            // B for next round (L2-resident); in flight across the barrier
            #pragma unroll
            for (int c = 0; c < 8; ++c) {
                bh[c] = *(const half8*)(bhp + (r + 1) * KROUND + c * 32);
                bl[c] = *(const half8*)(blp + (r + 1) * KROUND + c * 32);
            }
            __builtin_amdgcn_sched_barrier(0);
            // drain own DMA(r+1) (oldest 8); keep B(r+1) (newest 16) in flight
            asm volatile("s_waitcnt vmcnt(16)" ::: "memory");
            __builtin_amdgcn_sched_barrier(0);
            __builtin_amdgcn_s_barrier();     // all waves' DMA(r+1) drained; buf[r&1] free
            __builtin_amdgcn_sched_barrier(0);
            if (r < NR - 2) {
                #pragma unroll
                for (int i = 0; i < 8; ++i)
                    gl_lds16(asrc[i] + (r + 2) * KROUND, &stage[r & 1][wv * 8 + i][0]);
            }
        }
    }

    // ---- exchange: single plane; C layout col=lane&15, row=quad*4+reg ----
    const float inv = 1.0f / LOSCALE;
    #pragma unroll
    for (int mt = 0; mt < 2; ++mt)
        #pragma unroll
        for (int reg = 0; reg < 4; ++reg) {
            int tok = mt * 16 + quad * 4 + reg;
            xch[tok * LSTRIDE + wv * 16 + row16] = acc0[mt][reg] + acc1[mt][reg] * inv;
        }
    __syncthreads();

    // ---- epilogue: wave wv handles tokens [wv*8, wv*8+8); lane = expert ----
    float sp = 0.f, cnt = 0.f;
    for (int i = 0; i < 8; ++i) {
        int t = wv * 8 + i;
        float lg = xch[t * LSTRIDE + lane];

        float m = lg;
        #pragma unroll
        for (int off = 32; off; off >>= 1) m = fmaxf(m, __shfl_xor(m, off));
        float e = expf(lg - m);
        float ssum = e;
        #pragma unroll
        for (int off = 32; off; off >>= 1) ssum += __shfl_xor(ssum, off);
        float score = e / ssum;
        sp += score;

        int rank = 0;
        #pragma unroll
        for (int j = 0; j < 64; ++j) {
            float sj = __shfl(score, j);
            rank += (sj > score) || (sj == score && j < lane);
        }
        bool sel = rank < TOPK;

        float v = sel ? score : 0.f;
        #pragma unroll
        for (int off = 32; off; off >>= 1) v += __shfl_xor(v, off);

        if (sel) {
            out_w[(size_t)(tbase + t) * TOPK + rank] = score / v;
            out_i[(size_t)(tbase + t) * TOPK + rank] = (float)lane;
            cnt += 1.f;
        }
    }

    atomicAdd(&s_sp[lane], sp);
    atomicAdd(&s_cnt[lane], cnt);
    __syncthreads();
    const int rep = (blockIdx.x & (NREP - 1)) * NEXP;
    if (tid < 64)       atomicAdd(&cnt_ws[rep + tid], s_cnt[tid]);
    else if (tid < 128) atomicAdd(&sp_ws[rep + tid - 64], s_sp[tid - 64]);

    // release our atomics, then take a ticket; last block finalizes
    __threadfence();
    __syncthreads();
    if (tid == 0)
        s_last = (atomicAdd(ticket, 1u) == (unsigned)(gridDim.x - 1));
    __syncthreads();
    if (s_last && tid < 64) {
        float c = 0.f, p = 0.f;
        #pragma unroll
        for (int rr = 0; rr < NREP; ++rr) {
            c += atomicAdd(&cnt_ws[rr * NEXP + tid], 0.f);   // device-scope read
            p += atomicAdd(&sp_ws [rr * NEXP + tid], 0.f);
        }
        float v = (c / (float)(N_TOKENS * TOPK)) * (p / (float)N_TOKENS);
        #pragma unroll
        for (int off = 32; off; off >>= 1) v += __shfl_xor(v, off);
        if (tid == 0) out_aux[0] = 0.001f * (float)NEXP * v;
    }
}

extern "C" void kernel_launch(void* const* d_in, const int* in_sizes, int n_in,
                              void* d_out, int out_size, void* d_ws, size_t ws_size,
                              hipStream_t stream) {
    const float* A = (const float*)d_in[0];   // hidden_states (16384 x 2048)
    const float* W = (const float*)d_in[1];   // weight        (64 x 2048)
    float* out = (float*)d_out;

    _Float16*     whi    = (_Float16*)d_ws;
    _Float16*     wlo    = whi + (size_t)NEXP * DIM;
    float*        cnt_ws = (float*)(wlo + (size_t)NEXP * DIM);
    float*        sp_ws  = cnt_ws + (size_t)NREP * NEXP;
    unsigned int* ticket = (unsigned int*)(sp_ws + (size_t)NREP * NEXP);

    // zero cnt(8KB) + sp(8KB) + ticket(4B)
    hipMemsetAsync(cnt_ws, 0, 2 * NREP * NEXP * sizeof(float) + sizeof(unsigned int), stream);

    hipLaunchKernelGGL(wprep_kernel, dim3(NEXP * DIM / 256), dim3(256), 0, stream,
                       W, whi, wlo);

    float* out_w = out;
    float* out_i = out + (size_t)N_TOKENS * TOPK;
    float* out_a = out + 2 * (size_t)N_TOKENS * TOPK;

    hipLaunchKernelGGL(moe_kernel, dim3(NBLOCKS), dim3(256), 0, stream,
                       A, whi, wlo, out_w, out_i, out_a, cnt_ws, sp_ws, ticket);
}

// Round 9
// 219.236 us; speedup vs baseline: 1.1756x; 1.1542x over previous
//
#include <hip/hip_runtime.h>
#include <hip/hip_bf16.h>

#define N_TOKENS 16384
#define DIM      2048
#define NEXP     64
#define TOPK     8
#define LOSCALE  2048.0f      // 2^11, exact power of two
#define NBLOCKS  512          // 32 tokens per block
#define TOKPB    32
#define LSTRIDE  66           // exchange stride: <=2-way bank aliasing
#define NREP     32           // replicated aux accumulators
#define KROUND   256          // k per staging round
#define NR       8            // rounds (K = 2048)
#define SROW     528          // stage row stride in halves (1056 B): 16B-slot
                              // factor 66 == 2 mod 32 -> reader lanes land on
                              // slot 2*row16+quad = 2-way aliasing = FREE

typedef _Float16 half8   __attribute__((ext_vector_type(8)));
typedef float    floatx4 __attribute__((ext_vector_type(4)));

// ---------------------------------------------------------------------------
// Kernel 0: split W (64x2048 fp32) into f16 hi/lo planes.
//   whi = (f16)w;  wlo = (f16)((w - (f32)whi) * 2^11)
// ---------------------------------------------------------------------------
__global__ __launch_bounds__(256) void wprep_kernel(const float* __restrict__ W,
                                                    _Float16* __restrict__ Whi,
                                                    _Float16* __restrict__ Wlo) {
    int i = blockIdx.x * 256 + threadIdx.x;
    float w = W[i];
    _Float16 h = (_Float16)w;
    Whi[i] = h;
    Wlo[i] = (_Float16)((w - (float)h) * LOSCALE);
}

// split 8 f32 -> f16 hi/lo half8 pair
__device__ __forceinline__ void split2x8(const float4& f0, const float4& f1,
                                         half8& H, half8& L) {
    float v[8] = {f0.x, f0.y, f0.z, f0.w, f1.x, f1.y, f1.z, f1.w};
    #pragma unroll
    for (int j = 0; j < 8; ++j) {
        _Float16 h = (_Float16)v[j];
        H[j] = h;
        L[j] = (_Float16)((v[j] - (float)h) * LOSCALE);
    }
}

// stage this thread's 16 floats: hi halves at swh[0..16), lo at swl[0..16)
__device__ __forceinline__ void split_write(_Float16* swh, _Float16* swl,
                                            const float4& f0, const float4& f1,
                                            const float4& f2, const float4& f3) {
    half8 h, l;
    split2x8(f0, f1, h, l);
    *(half8*)(swh)     = h;
    *(half8*)(swl)     = l;
    split2x8(f2, f3, h, l);
    *(half8*)(swh + 8) = h;
    *(half8*)(swl + 8) = l;
}

// ---------------------------------------------------------------------------
// R9: R5's structure (best measured: reg-staged LDS, one sync per round) at
// DOUBLE the wave residency, with conflict-free stage reads and the aux
// finalize moved behind a kernel boundary.
//
// Evidence: R5=105us was the best of 7 structures, all at 2 waves/SIMD, all
// pipes <20% busy. R2/R3's "more waves hurt" were confounded (R2: arg2
// destroyed the pipeline, VGPR 84; R3: 2x B-traffic + scattered loads).
// This tests 4 waves/SIMD with the winning structure intact:
//   - 8 waves = experts(4) x K-half(2); block = 32 tokens; 512 blocks
//     -> 2 blocks/CU x 8 waves = 16 waves/CU. acc = 16 VGPR/wave.
//   - per 256-k round: 512 threads stage 32x256 f32 (64B contiguous per
//     thread), split f32->f16 hi/lo ONCE, write [hi256|lo256] rows of
//     stride 528 halves -> ds_read_b128 readers are 2-way (free).
//   - A prefetch: next round's 4 float4 issued at round start (R5 pattern);
//     B (L2-resident) reloaded in place per chunk for round r+1.
//   - one __syncthreads per round (R5's schedule; beat counted-vmcnt R8).
//   - epilogue: xch aliases the stage buffer (saves 17KB LDS); 2 k-half
//     partials summed; softmax + rank-select (lax.top_k semantics).
//   - aux: block atomics into NREP replicas; NO fence/ticket -- separate
//     aux_kernel after the stream boundary does plain-load reduction.
// ---------------------------------------------------------------------------
__global__ __launch_bounds__(512) void moe_kernel(const float* __restrict__ A,
                                                  const _Float16* __restrict__ Whi,
                                                  const _Float16* __restrict__ Wlo,
                                                  float* __restrict__ out_w,
                                                  float* __restrict__ out_i,
                                                  float* __restrict__ cnt_ws,
                                                  float* __restrict__ sp_ws) {
    __shared__ _Float16 stage[2][TOKPB][SROW];   // 67.6 KB (reused as xch)
    __shared__ float    s_cnt[NEXP];
    __shared__ float    s_sp[NEXP];

    const int tid   = threadIdx.x;
    const int lane  = tid & 63;
    const int wv    = tid >> 6;      // 0..7
    const int es    = wv & 3;        // expert slab: experts [16es, 16es+16)
    const int kh    = wv >> 2;       // k half: [kh*128, kh*128+128) per round
    const int row16 = lane & 15;
    const int quad  = lane >> 4;
    const int tbase = blockIdx.x * TOKPB;

    if (tid < NEXP) { s_cnt[tid] = 0.f; s_sp[tid] = 0.f; }

    // ---- stager role: thread covers token row (tid>>4), 64B seg (tid&15) ----
    const int sr = tid >> 4;
    const int ss = tid & 15;
    const float* Ap = A + (size_t)(tbase + sr) * DIM + ss * 16;
    _Float16* swh0 = &stage[0][sr][0] + ss * 16;
    _Float16* swh1 = &stage[1][sr][0] + ss * 16;

    // ---- MFMA role ----
    const _Float16* bhp = Whi + (size_t)(es * 16 + row16) * DIM + kh * 128 + quad * 8;
    const _Float16* blp = Wlo + (size_t)(es * 16 + row16) * DIM + kh * 128 + quad * 8;

    floatx4 acc0[2] = {};   // hi*hi         (mt = 0,1)
    floatx4 acc1[2] = {};   // hi*lo + lo*hi (carries 2^11)
    half8 bh[4], bl[4];

    // ---- prologue: stage round 0; preload B round 0 ----
    {
        float4 f0 = *(const float4*)(Ap);
        float4 f1 = *(const float4*)(Ap + 4);
        float4 f2 = *(const float4*)(Ap + 8);
        float4 f3 = *(const float4*)(Ap + 12);
        split_write(swh0, swh0 + 256, f0, f1, f2, f3);
    }
    #pragma unroll
    for (int c = 0; c < 4; ++c) {
        bh[c] = *(const half8*)(bhp + c * 32);
        bl[c] = *(const half8*)(blp + c * 32);
    }
    __syncthreads();

    // ---- main loop: 8 rounds of 256 k ----
    for (int r = 0; r < NR; ++r) {
        float4 g0, g1, g2, g3;
        if (r < NR - 1) {                  // issue next round's A loads NOW
            const float* p = Ap + (r + 1) * KROUND;
            g0 = *(const float4*)(p);
            g1 = *(const float4*)(p + 4);
            g2 = *(const float4*)(p + 8);
            g3 = *(const float4*)(p + 12);
        }
        const _Float16* sb = &stage[r & 1][0][0];

        #pragma unroll
        for (int c = 0; c < 4; ++c) {
            const int k0 = kh * 128 + c * 32 + quad * 8;
            const _Float16* p0 = sb + row16 * SROW;
            const _Float16* p1 = sb + (16 + row16) * SROW;
            half8 a0h = *(const half8*)(p0 + k0);
            half8 a0l = *(const half8*)(p0 + 256 + k0);
            half8 a1h = *(const half8*)(p1 + k0);
            half8 a1l = *(const half8*)(p1 + 256 + k0);
            acc0[0] = __builtin_amdgcn_mfma_f32_16x16x32_f16(a0h, bh[c], acc0[0], 0, 0, 0);
            acc1[0] = __builtin_amdgcn_mfma_f32_16x16x32_f16(a0h, bl[c], acc1[0], 0, 0, 0);
            acc1[0] = __builtin_amdgcn_mfma_f32_16x16x32_f16(a0l, bh[c], acc1[0], 0, 0, 0);
            acc0[1] = __builtin_amdgcn_mfma_f32_16x16x32_f16(a1h, bh[c], acc0[1], 0, 0, 0);
            acc1[1] = __builtin_amdgcn_mfma_f32_16x16x32_f16(a1h, bl[c], acc1[1], 0, 0, 0);
            acc1[1] = __builtin_amdgcn_mfma_f32_16x16x32_f16(a1l, bh[c], acc1[1], 0, 0, 0);
            if (r < NR - 1) {              // in-place B reload for round r+1
                bh[c] = *(const half8*)(bhp + (r + 1) * KROUND + c * 32);
                bl[c] = *(const half8*)(blp + (r + 1) * KROUND + c * 32);
            }
        }

        if (r < NR - 1) {
            _Float16* swh = (r & 1) ? swh0 : swh1;
            split_write(swh, swh + 256, g0, g1, g2, g3);
        }
        __syncthreads();
    }

    // ---- exchange (xch aliases stage): [2 khalf][32 tok][66] ----
    float* xch = (float*)&stage[0][0][0];
    const float inv = 1.0f / LOSCALE;
    #pragma unroll
    for (int mt = 0; mt < 2; ++mt)
        #pragma unroll
        for (int reg = 0; reg < 4; ++reg) {
            int tok = mt * 16 + quad * 4 + reg;
            xch[(kh * TOKPB + tok) * LSTRIDE + es * 16 + row16] =
                acc0[mt][reg] + acc1[mt][reg] * inv;
        }
    __syncthreads();

    // ---- epilogue: wave wv handles tokens [wv*4, wv*4+4); lane = expert ----
    float sp = 0.f, cnt = 0.f;
    for (int i = 0; i < 4; ++i) {
        int t = wv * 4 + i;
        float lg = xch[t * LSTRIDE + lane] + xch[(TOKPB + t) * LSTRIDE + lane];

        float m = lg;
        #pragma unroll
        for (int off = 32; off; off >>= 1) m = fmaxf(m, __shfl_xor(m, off));
        float e = expf(lg - m);
        float ssum = e;
        #pragma unroll
        for (int off = 32; off; off >>= 1) ssum += __shfl_xor(ssum, off);
        float score = e / ssum;
        sp += score;

        int rank = 0;
        #pragma unroll
        for (int j = 0; j < 64; ++j) {
            float sj = __shfl(score, j);
            rank += (sj > score) || (sj == score && j < lane);
        }
        bool sel = rank < TOPK;

        float v = sel ? score : 0.f;
        #pragma unroll
        for (int off = 32; off; off >>= 1) v += __shfl_xor(v, off);

        if (sel) {
            out_w[(size_t)(tbase + t) * TOPK + rank] = score / v;
            out_i[(size_t)(tbase + t) * TOPK + rank] = (float)lane;
            cnt += 1.f;
        }
    }

    atomicAdd(&s_sp[lane], sp);
    atomicAdd(&s_cnt[lane], cnt);
    __syncthreads();
    const int rep = (blockIdx.x & (NREP - 1)) * NEXP;
    if (tid < 64)       atomicAdd(&cnt_ws[rep + tid], s_cnt[tid]);
    else if (tid < 128) atomicAdd(&sp_ws[rep + tid - 64], s_sp[tid - 64]);
    // no fence/ticket: aux_kernel after the kernel boundary reduces replicas
}

// ---------------------------------------------------------------------------
// Kernel 2: reduce NREP replicas -> aux loss. Kernel boundary guarantees
// visibility of moe_kernel's device-scope atomics; plain loads suffice.
// ---------------------------------------------------------------------------
__global__ __launch_bounds__(64) void aux_kernel(const float* __restrict__ cnt_ws,
                                                 const float* __restrict__ sp_ws,
                                                 float* __restrict__ out_aux) {
    int tid = threadIdx.x;
    float c = 0.f, p = 0.f;
    #pragma unroll
    for (int r = 0; r < NREP; ++r) {
        c += cnt_ws[r * NEXP + tid];
        p += sp_ws[r * NEXP + tid];
    }
    float v = (c / (float)(N_TOKENS * TOPK)) * (p / (float)N_TOKENS);
    #pragma unroll
    for (int off = 32; off; off >>= 1) v += __shfl_xor(v, off);
    if (tid == 0) out_aux[0] = 0.001f * (float)NEXP * v;
}

extern "C" void kernel_launch(void* const* d_in, const int* in_sizes, int n_in,
                              void* d_out, int out_size, void* d_ws, size_t ws_size,
                              hipStream_t stream) {
    const float* A = (const float*)d_in[0];   // hidden_states (16384 x 2048)
    const float* W = (const float*)d_in[1];   // weight        (64 x 2048)
    float* out = (float*)d_out;

    _Float16* whi    = (_Float16*)d_ws;
    _Float16* wlo    = whi + (size_t)NEXP * DIM;
    float*    cnt_ws = (float*)(wlo + (size_t)NEXP * DIM);
    float*    sp_ws  = cnt_ws + (size_t)NREP * NEXP;

    // zero cnt(8KB) + sp(8KB)
    hipMemsetAsync(cnt_ws, 0, 2 * NREP * NEXP * sizeof(float), stream);

    hipLaunchKernelGGL(wprep_kernel, dim3(NEXP * DIM / 256), dim3(256), 0, stream,
                       W, whi, wlo);

    float* out_w = out;
    float* out_i = out + (size_t)N_TOKENS * TOPK;
    float* out_a = out + 2 * (size_t)N_TOKENS * TOPK;

    hipLaunchKernelGGL(moe_kernel, dim3(NBLOCKS), dim3(512), 0, stream,
                       A, whi, wlo, out_w, out_i, cnt_ws, sp_ws);

    hipLaunchKernelGGL(aux_kernel, dim3(1), dim3(64), 0, stream,
                       cnt_ws, sp_ws, out_a);
}